// Round 2
// 554.186 us; speedup vs baseline: 1.0625x; 1.0625x over previous
//
#include <hip/hip_runtime.h>

#define SS 2048
#define RR 384
#define CED 64
// H = 8, C = 8, H*C = 64

typedef __attribute__((ext_vector_type(8))) short bf16x8;
typedef __attribute__((ext_vector_type(4))) float f32x4;

__device__ __forceinline__ short f2bf(float f) {
  union { float f; unsigned u; } v; v.f = f;
  unsigned u = v.u;
  u += 0x7fffu + ((u >> 16) & 1u);   // RNE
  return (short)(u >> 16);
}
__device__ __forceinline__ float bf2f(short s) {
  union { unsigned u; float f; } v;
  v.u = ((unsigned)(unsigned short)s) << 16;
  return v.f;
}

// ---------------- kernel W: weights -> bf16 in workspace ----------------
__global__ __launch_bounds__(256) void kW(const float* __restrict__ Wk,
                                          const float* __restrict__ Wv,
                                          const float* __restrict__ Wg,
                                          const float* __restrict__ Wo,
                                          short* __restrict__ wkv,
                                          short* __restrict__ wgb,
                                          short* __restrict__ wob) {
  int t = blockIdx.x * 256 + threadIdx.x;
  if (t < 1024) {  // wkv[16][64]: rows 0..7 = Wk, 8..15 = Wv
    int c16 = t >> 6, ce = t & 63;
    float v = (c16 < 8) ? Wk[c16 * 64 + ce] : Wv[(c16 - 8) * 64 + ce];
    wkv[t] = f2bf(v);
  }
  if (t < 4096) {
    wgb[t] = f2bf(Wg[t]);
    wob[t] = f2bf(Wo[t]);
  }
}

// ---------------- kernel A: per-r pooling, K/V, softmax, o[r][64] ----------------
__global__ __launch_bounds__(256) void kA(const float* __restrict__ m,
                                          const float* __restrict__ mask,
                                          const float* __restrict__ Wq,
                                          const short* __restrict__ wkv,
                                          float* __restrict__ o_ws) {
  __shared__ __align__(16) short kv[SS][16];   // cols 0..7 k (later p), 8..15 v
  __shared__ __align__(16) float qs[64];
  __shared__ __align__(16) float qpart[4][64];
  __shared__ float redmax[4][8];
  __shared__ float redsum[4][8];
  __shared__ float ored[4][64];
  __shared__ float qden_l[4];

  const int r = blockIdx.x;
  const int tid = threadIdx.x;
  const int wave = tid >> 6, lane = tid & 63;
  const int l15 = lane & 15, quad = lane >> 4;

  // B-fragments of [Wk;Wv] (row-major [16][64] bf16): lane holds B[k=quad*8+j][n=l15]
  bf16x8 bkv0 = *(const bf16x8*)(wkv + l15 * 64 + quad * 8);
  bf16x8 bkv1 = *(const bf16x8*)(wkv + l15 * 64 + 32 + quad * 8);

  float qdp = 0.f;
  float pp[16];
#pragma unroll
  for (int i = 0; i < 16; i++) pp[i] = 0.f;

  // ---- pass 1: K,V via MFMA + masked pooling (register-accumulated) ----
  for (int s0 = wave * 16; s0 < SS; s0 += 64) {
    const int row = s0 + l15;
    const float* mrow = m + ((size_t)r * SS + row) * CED;
    f32x4 a0 = *(const f32x4*)(mrow + quad * 8);
    f32x4 a1 = *(const f32x4*)(mrow + quad * 8 + 4);
    f32x4 a2 = *(const f32x4*)(mrow + 32 + quad * 8);
    f32x4 a3 = *(const f32x4*)(mrow + 32 + quad * 8 + 4);
    float mk = mask[r * SS + row];
    qdp += mk;

    pp[0] += a0.x * mk;  pp[1] += a0.y * mk;  pp[2] += a0.z * mk;  pp[3] += a0.w * mk;
    pp[4] += a1.x * mk;  pp[5] += a1.y * mk;  pp[6] += a1.z * mk;  pp[7] += a1.w * mk;
    pp[8] += a2.x * mk;  pp[9] += a2.y * mk;  pp[10] += a2.z * mk; pp[11] += a2.w * mk;
    pp[12] += a3.x * mk; pp[13] += a3.y * mk; pp[14] += a3.z * mk; pp[15] += a3.w * mk;

    bf16x8 af0 = {f2bf(a0.x), f2bf(a0.y), f2bf(a0.z), f2bf(a0.w),
                  f2bf(a1.x), f2bf(a1.y), f2bf(a1.z), f2bf(a1.w)};
    bf16x8 af1 = {f2bf(a2.x), f2bf(a2.y), f2bf(a2.z), f2bf(a2.w),
                  f2bf(a3.x), f2bf(a3.y), f2bf(a3.z), f2bf(a3.w)};
    f32x4 acc = {0.f, 0.f, 0.f, 0.f};
    acc = __builtin_amdgcn_mfma_f32_16x16x32_bf16(af0, bkv0, acc, 0, 0, 0);
    acc = __builtin_amdgcn_mfma_f32_16x16x32_bf16(af1, bkv1, acc, 0, 0, 0);
    // D layout: row = quad*4+rg (s within tile), col = l15 (kv index)
#pragma unroll
    for (int rg = 0; rg < 4; rg++)
      kv[s0 + quad * 4 + rg][l15] = f2bf(acc[rg]);
  }

  // single pooling butterfly across l15 (rows), once
#pragma unroll
  for (int d = 1; d < 16; d <<= 1) {
#pragma unroll
    for (int i = 0; i < 16; i++) pp[i] += __shfl_xor(pp[i], d);
  }
#pragma unroll
  for (int d = 1; d < 16; d <<= 1) qdp += __shfl_xor(qdp, d);
  if (l15 == 0) {
#pragma unroll
    for (int i = 0; i < 8; i++) {
      qpart[wave][quad * 8 + i] = pp[i];
      qpart[wave][32 + quad * 8 + i] = pp[8 + i];
    }
  }
  if (lane == 0) qden_l[wave] = qdp;
  __syncthreads();

  // ---- q projection (wave 0, lane = hc) ----
  if (wave == 0) {
    float qden = qden_l[0] + qden_l[1] + qden_l[2] + qden_l[3] + 1e-10f;
    float inv = 1.f / qden;
    const float* wqrow = Wq + lane * CED;
    float acc = 0.f;
    for (int ce = 0; ce < CED; ce++) {
      float qv = qpart[0][ce] + qpart[1][ce] + qpart[2][ce] + qpart[3][ce];
      acc += qv * wqrow[ce];
    }
    qs[lane] = acc * inv * 0.35355339059327373f;  // * sqrt(1/C)
  }
  __syncthreads();

  // ---- logits (thread owns 8 positions, 8 heads each, in registers) ----
  float q[64];
#pragma unroll
  for (int i = 0; i < 16; i++) ((f32x4*)q)[i] = ((const f32x4*)qs)[i];

  float lg[8][8];
  float mx[8];
#pragma unroll
  for (int h = 0; h < 8; h++) mx[h] = -3.0e38f;

#pragma unroll
  for (int j = 0; j < 8; j++) {
    int s = tid + 256 * j;
    bf16x8 k8 = *(const bf16x8*)&kv[s][0];
    float kf[8];
#pragma unroll
    for (int c = 0; c < 8; c++) kf[c] = bf2f(k8[c]);
    float bias = (mask[r * SS + s] - 1.f) * 1e9f;
#pragma unroll
    for (int h = 0; h < 8; h++) {
      float a = bias;
#pragma unroll
      for (int c = 0; c < 8; c++) a += q[h * 8 + c] * kf[c];
      lg[j][h] = a;
      mx[h] = fmaxf(mx[h], a);
    }
  }
#pragma unroll
  for (int d = 1; d < 64; d <<= 1) {
#pragma unroll
    for (int h = 0; h < 8; h++) mx[h] = fmaxf(mx[h], __shfl_xor(mx[h], d));
  }
  if (lane == 0) {
#pragma unroll
    for (int h = 0; h < 8; h++) redmax[wave][h] = mx[h];
  }
  __syncthreads();
  float Mh[8];
#pragma unroll
  for (int h = 0; h < 8; h++)
    Mh[h] = fmaxf(fmaxf(redmax[0][h], redmax[1][h]),
                  fmaxf(redmax[2][h], redmax[3][h]));

  // ---- exp + sum; p overwrites k slots (own positions only, post-barrier) ----
  float sm[8] = {0, 0, 0, 0, 0, 0, 0, 0};
#pragma unroll
  for (int j = 0; j < 8; j++) {
    int s = tid + 256 * j;
#pragma unroll
    for (int h = 0; h < 8; h++) {
      float p = __expf(lg[j][h] - Mh[h]);
      sm[h] += p;
      kv[s][h] = f2bf(p);
    }
  }
#pragma unroll
  for (int d = 1; d < 64; d <<= 1) {
#pragma unroll
    for (int h = 0; h < 8; h++) sm[h] += __shfl_xor(sm[h], d);
  }
  if (lane == 0) {
#pragma unroll
    for (int h = 0; h < 8; h++) redsum[wave][h] = sm[h];
  }
  __syncthreads();

  // ---- o[h][c] = sum_s p[s][h] * v[s][c] ----
  {
    int h = (tid >> 3) & 7, c = tid & 7, q4 = tid >> 6;
    float a0 = 0, a1 = 0, a2 = 0, a3 = 0;
    int sbeg = q4 * 512;
    for (int s = sbeg; s < sbeg + 512; s += 4) {
      a0 += bf2f(kv[s][h]) * bf2f(kv[s][8 + c]);
      a1 += bf2f(kv[s + 1][h]) * bf2f(kv[s + 1][8 + c]);
      a2 += bf2f(kv[s + 2][h]) * bf2f(kv[s + 2][8 + c]);
      a3 += bf2f(kv[s + 3][h]) * bf2f(kv[s + 3][8 + c]);
    }
    ored[q4][tid & 63] = (a0 + a1) + (a2 + a3);
  }
  __syncthreads();
  if (tid < 64) {
    int h = tid >> 3;
    float ssum = redsum[0][h] + redsum[1][h] + redsum[2][h] + redsum[3][h];
    float o = ored[0][tid] + ored[1][tid] + ored[2][tid] + ored[3][tid];
    o_ws[r * 64 + tid] = o / ssum;
  }
}

// ---------------- kernel B: gate GEMM + out-proj GEMM + residual ----------------
// v2 (s-major remap): block = one s, loop over 6 r-tiles of 64.
// add_to/out ([S][R][CE], the HBM-bound arrays) become fully sequential
// streams (16 KB/iter, 98 KB contiguous per block) instead of 64x256B cells
// at 96 KB stride (DRAM row-activate thrash -> 2.15 TB/s measured). m becomes
// the scattered array but is Infinity-Cache-resident (FETCH_SIZE showed m
// never touched HBM in kB). Next m tile is register-prefetched one iteration
// ahead; add_to is issued at iter start and consumed at iter end.
__global__ __launch_bounds__(256) void kB(const float* __restrict__ m,
                                          const float* __restrict__ add_to,
                                          const float* __restrict__ bg,
                                          const float* __restrict__ bo,
                                          const float* __restrict__ o_ws,
                                          const short* __restrict__ wg,
                                          const short* __restrict__ wo,
                                          float* __restrict__ out) {
  __shared__ __align__(16) short Tl[64][72];  // T bf16, padded
  __shared__ __align__(16) float Yl[64][68];  // Y fp32, padded

  const int s = blockIdx.x;        // one s per block, 2048 blocks
  const int tid = threadIdx.x;
  const int wave = tid >> 6, lane = tid & 63;
  const int l15 = lane & 15, quad = lane >> 4;
  const int sp = tid >> 2, cb = (tid & 3) * 16;

  // weight B-fragments (row-major bf16 [n][k]): lane reads 8 contiguous k of row n
  bf16x8 wgf[4][2], wof[4][2];
#pragma unroll
  for (int nt = 0; nt < 4; nt++) {
#pragma unroll
    for (int kc = 0; kc < 2; kc++) {
      wgf[nt][kc] = *(const bf16x8*)(wg + (nt * 16 + l15) * 64 + kc * 32 + quad * 8);
      wof[nt][kc] = *(const bf16x8*)(wo + (nt * 16 + l15) * 64 + kc * 32 + quad * 8);
    }
  }
  float bgv[4];
#pragma unroll
  for (int nt = 0; nt < 4; nt++) bgv[nt] = bg[nt * 16 + l15];
  f32x4 bov[4];
#pragma unroll
  for (int i = 0; i < 4; i++) bov[i] = *(const f32x4*)(bo + cb + i * 4);

  // prefetch m tile for rt=0 (rows r = wave*16+l15, column s)
  f32x4 mc[4];
  {
    const float* mp = m + ((size_t)(wave * 16 + l15) * SS + s) * CED;
    mc[0] = *(const f32x4*)(mp + quad * 8);
    mc[1] = *(const f32x4*)(mp + quad * 8 + 4);
    mc[2] = *(const f32x4*)(mp + 32 + quad * 8);
    mc[3] = *(const f32x4*)(mp + 32 + quad * 8 + 4);
  }

#pragma unroll
  for (int rt = 0; rt < 6; rt++) {
    const int r0 = rt * 64;

    // ---- prefetch next r-tile of m (consumed next iteration) ----
    f32x4 mn[4];
    if (rt < 5) {
      const float* mp = m + ((size_t)(r0 + 64 + wave * 16 + l15) * SS + s) * CED;
      mn[0] = *(const f32x4*)(mp + quad * 8);
      mn[1] = *(const f32x4*)(mp + quad * 8 + 4);
      mn[2] = *(const f32x4*)(mp + 32 + quad * 8);
      mn[3] = *(const f32x4*)(mp + 32 + quad * 8 + 4);
    }

    // ---- add_to for current tile: contiguous 16 KB, consumed at iter end ----
    const float* ap = add_to + ((size_t)s * RR + r0 + sp) * CED + cb;
    f32x4 at0 = ((const f32x4*)ap)[0];
    f32x4 at1 = ((const f32x4*)ap)[1];
    f32x4 at2 = ((const f32x4*)ap)[2];
    f32x4 at3 = ((const f32x4*)ap)[3];

    // ---- o[r][hc] for this tile's rows (L2-hot, 16 scalars/lane) ----
    float o16[4][4];  // [rg][nt]
    {
      const float* ob = o_ws + (r0 + wave * 16 + quad * 4) * 64 + l15;
#pragma unroll
      for (int rg = 0; rg < 4; rg++)
#pragma unroll
        for (int nt = 0; nt < 4; nt++)
          o16[rg][nt] = ob[rg * 64 + nt * 16];
    }

    // ---- GEMM1: P = M(64r x 64ce) @ Wg^T ----
    f32x4 acc[4] = {{0,0,0,0},{0,0,0,0},{0,0,0,0},{0,0,0,0}};
    {
      bf16x8 af0 = {f2bf(mc[0].x), f2bf(mc[0].y), f2bf(mc[0].z), f2bf(mc[0].w),
                    f2bf(mc[1].x), f2bf(mc[1].y), f2bf(mc[1].z), f2bf(mc[1].w)};
      bf16x8 af1 = {f2bf(mc[2].x), f2bf(mc[2].y), f2bf(mc[2].z), f2bf(mc[2].w),
                    f2bf(mc[3].x), f2bf(mc[3].y), f2bf(mc[3].z), f2bf(mc[3].w)};
#pragma unroll
      for (int nt = 0; nt < 4; nt++) {
        acc[nt] = __builtin_amdgcn_mfma_f32_16x16x32_bf16(af0, wgf[nt][0], acc[nt], 0, 0, 0);
        acc[nt] = __builtin_amdgcn_mfma_f32_16x16x32_bf16(af1, wgf[nt][1], acc[nt], 0, 0, 0);
      }
    }
    // epilogue1: sigmoid gate * o[row][hc]  ->  T (bf16) in LDS
#pragma unroll
    for (int nt = 0; nt < 4; nt++) {
#pragma unroll
      for (int rg = 0; rg < 4; rg++) {
        float val = acc[nt][rg] + bgv[nt];
        float gt = 1.f / (1.f + __expf(-val));
        Tl[wave * 16 + quad * 4 + rg][nt * 16 + l15] = f2bf(gt * o16[rg][nt]);
      }
    }
    __syncthreads();

    // ---- GEMM2: Y = T @ Wo^T ----
    f32x4 acc2[4] = {{0,0,0,0},{0,0,0,0},{0,0,0,0},{0,0,0,0}};
#pragma unroll
    for (int kc = 0; kc < 2; kc++) {
      bf16x8 af = *(const bf16x8*)&Tl[wave * 16 + l15][kc * 32 + quad * 8];
#pragma unroll
      for (int nt = 0; nt < 4; nt++)
        acc2[nt] = __builtin_amdgcn_mfma_f32_16x16x32_bf16(af, wof[nt][kc], acc2[nt], 0, 0, 0);
    }
#pragma unroll
    for (int nt = 0; nt < 4; nt++) {
#pragma unroll
      for (int rg = 0; rg < 4; rg++)
        Yl[wave * 16 + quad * 4 + rg][nt * 16 + l15] = acc2[nt][rg];
    }
    __syncthreads();

    // ---- coalesced fused epilogue: out = add_to + Y + bo (16 KB contiguous) ----
    float* op = out + ((size_t)s * RR + r0 + sp) * CED + cb;
    f32x4 y0 = *(const f32x4*)&Yl[sp][cb];
    f32x4 y1 = *(const f32x4*)&Yl[sp][cb + 4];
    f32x4 y2 = *(const f32x4*)&Yl[sp][cb + 8];
    f32x4 y3 = *(const f32x4*)&Yl[sp][cb + 12];
    ((f32x4*)op)[0] = at0 + y0 + bov[0];
    ((f32x4*)op)[1] = at1 + y1 + bov[1];
    ((f32x4*)op)[2] = at2 + y2 + bov[2];
    ((f32x4*)op)[3] = at3 + y3 + bov[3];

    // rotate prefetch registers (fully unrolled -> static renaming)
    if (rt < 5) {
      mc[0] = mn[0]; mc[1] = mn[1]; mc[2] = mn[2]; mc[3] = mn[3];
    }
  }
}

extern "C" void kernel_launch(void* const* d_in, const int* in_sizes, int n_in,
                              void* d_out, int out_size, void* d_ws, size_t ws_size,
                              hipStream_t stream) {
  const float* m      = (const float*)d_in[0];
  const float* mask   = (const float*)d_in[1];
  const float* Wq     = (const float*)d_in[2];
  const float* Wk     = (const float*)d_in[3];
  const float* Wv     = (const float*)d_in[4];
  const float* Wg     = (const float*)d_in[5];
  const float* bg     = (const float*)d_in[6];
  const float* Wo     = (const float*)d_in[7];
  const float* bo     = (const float*)d_in[8];
  const float* add_to = (const float*)d_in[9];
  float* out = (float*)d_out;

  char* ws = (char*)d_ws;
  float* o_ws = (float*)ws;                          // 384*64*4 = 98304 B
  short* wkv  = (short*)(ws + 98304);                // 16*64*2  = 2048 B
  short* wgb  = (short*)(ws + 98304 + 2048);         // 64*64*2  = 8192 B
  short* wob  = (short*)(ws + 98304 + 2048 + 8192);  // 64*64*2  = 8192 B

  hipLaunchKernelGGL(kW, dim3(16),   dim3(256), 0, stream, Wk, Wv, Wg, Wo, wkv, wgb, wob);
  hipLaunchKernelGGL(kA, dim3(384),  dim3(256), 0, stream, m, mask, Wq, wkv, o_ws);
  hipLaunchKernelGGL(kB, dim3(2048), dim3(256), 0, stream, m, add_to, bg, bo, o_ws, wgb, wob, out);
}